// Round 2
// baseline (87.587 us; speedup 1.0000x reference)
//
#include <hip/hip_runtime.h>
#include <math.h>

// Distance kernel: out[b,n,m,{cos,p1,p2}] for x[B,N,D], y[M,D], D=128.
// R = B*N rows. Vector-fp32 compute-bound (no fp32 MFMA on CDNA4).
// Block = 256 threads = 2 d-groups x 128 threads. Each d-group handles 16 of
// 32 float4-chunks of D; thread tile 4x4 pairs; block tile 32n x 64m.
// LDS reads per CU cut 33% vs 2x4 full-D tile; register ping-pong prefetch
// hides ds_read latency at 2 waves/SIMD. Final cross-group reduce via LDS.

#define DDIM 128
#define BN 32
#define BM 64
#define TN 4
#define TM 4
#define PADW 132   // floats per LDS row (128 + 4): row stride 4 banks, b128-aligned
#define HC 16      // chunks (of 4 dims) per d-group

__global__ __launch_bounds__(256, 2) void distance_kernel(
    const float* __restrict__ x, const float* __restrict__ y,
    float* __restrict__ out, int R, int M)
{
    __shared__ float xs[BN * PADW];
    __shared__ float ys[BM * PADW];
    __shared__ float xrn[BN];
    __shared__ float yrn[BM];
    __shared__ float red[128 * 48];   // cross-d-group partials: 24.6 KB

    const int t  = threadIdx.x;
    const int n0 = blockIdx.x * BN;
    const int m0 = blockIdx.y * BM;

    // ---- Stage x tile (32 rows) and y tile (64 rows), float4 coalesced ----
    {
        const float4* xg = (const float4*)(x + (size_t)n0 * DDIM);
        #pragma unroll
        for (int k = 0; k < (BN * DDIM / 4) / 256; ++k) {   // 4 iters
            int idx = t + 256 * k;
            int row = idx >> 5;
            int c   = idx & 31;
            float4 v = xg[(row << 5) + c];
            *(float4*)&xs[row * PADW + (c << 2)] = v;
        }
        const float4* yg = (const float4*)(y + (size_t)m0 * DDIM);
        #pragma unroll
        for (int k = 0; k < (BM * DDIM / 4) / 256; ++k) {   // 8 iters
            int idx = t + 256 * k;
            int row = idx >> 5;
            int c   = idx & 31;
            float4 v = yg[(row << 5) + c];
            *(float4*)&ys[row * PADW + (c << 2)] = v;
        }
    }
    __syncthreads();

    // ---- Cooperative per-row rsqrt norms (for cosine) ----
    if (t < BN) {
        float s = 0.f;
        const float4* r = (const float4*)&xs[t * PADW];
        #pragma unroll
        for (int c = 0; c < DDIM / 4; ++c) {
            float4 v = r[c];
            s += v.x * v.x + v.y * v.y + v.z * v.z + v.w * v.w;
        }
        xrn[t] = rsqrtf(s);
    } else if (t >= 64 && t < 64 + BM) {
        int row = t - 64;
        float s = 0.f;
        const float4* r = (const float4*)&ys[row * PADW];
        #pragma unroll
        for (int c = 0; c < DDIM / 4; ++c) {
            float4 v = r[c];
            s += v.x * v.x + v.y * v.y + v.z * v.z + v.w * v.w;
        }
        yrn[row] = rsqrtf(s);
    }
    __syncthreads();

    // ---- Main loop: d-group g covers chunks [g*16, g*16+16) ----
    const int g  = t >> 7;      // 0 or 1
    const int tl = t & 127;
    const int lm = tl & 15;     // m = m0 + lm + 16*j
    const int ln = tl >> 4;     // n = n0 + ln + 8*i   (ln in 0..7)
    const int cb = g * HC;

    float dot[TN][TM] = {};
    float p1 [TN][TM] = {};
    float p2 [TN][TM] = {};

    float4 xA[TN], yA[TM];
    #pragma unroll
    for (int i = 0; i < TN; ++i)
        xA[i] = *(const float4*)&xs[(ln + 8 * i) * PADW + (cb << 2)];
    #pragma unroll
    for (int j = 0; j < TM; ++j)
        yA[j] = *(const float4*)&ys[(lm + 16 * j) * PADW + (cb << 2)];

    #pragma unroll 4
    for (int cc = 0; cc < HC; ++cc) {
        float4 xB[TN], yB[TM];
        if (cc < HC - 1) {   // prefetch next chunk while computing this one
            int c1 = cb + cc + 1;
            #pragma unroll
            for (int i = 0; i < TN; ++i)
                xB[i] = *(const float4*)&xs[(ln + 8 * i) * PADW + (c1 << 2)];
            #pragma unroll
            for (int j = 0; j < TM; ++j)
                yB[j] = *(const float4*)&ys[(lm + 16 * j) * PADW + (c1 << 2)];
        }

        #pragma unroll
        for (int i = 0; i < TN; ++i) {
            #pragma unroll
            for (int j = 0; j < TM; ++j) {
                float d0 = xA[i].x - yA[j].x;
                float d1 = xA[i].y - yA[j].y;
                float d2 = xA[i].z - yA[j].z;
                float d3 = xA[i].w - yA[j].w;
                p1[i][j] += fabsf(d0); p2[i][j] = fmaf(d0, d0, p2[i][j]);
                dot[i][j] = fmaf(xA[i].x, yA[j].x, dot[i][j]);
                p1[i][j] += fabsf(d1); p2[i][j] = fmaf(d1, d1, p2[i][j]);
                dot[i][j] = fmaf(xA[i].y, yA[j].y, dot[i][j]);
                p1[i][j] += fabsf(d2); p2[i][j] = fmaf(d2, d2, p2[i][j]);
                dot[i][j] = fmaf(xA[i].z, yA[j].z, dot[i][j]);
                p1[i][j] += fabsf(d3); p2[i][j] = fmaf(d3, d3, p2[i][j]);
                dot[i][j] = fmaf(xA[i].w, yA[j].w, dot[i][j]);
            }
        }

        if (cc < HC - 1) {
            #pragma unroll
            for (int i = 0; i < TN; ++i) xA[i] = xB[i];
            #pragma unroll
            for (int j = 0; j < TM; ++j) yA[j] = yB[j];
        }
    }

    // ---- Cross-d-group reduce: g1 dumps partials, g0 combines + epilogue ----
    __syncthreads();
    if (g == 1) {
        float* r = &red[tl * 48];
        #pragma unroll
        for (int i = 0; i < TN; ++i)
            #pragma unroll
            for (int j = 0; j < TM; ++j) {
                int k = (i * TM + j) * 3;
                r[k + 0] = dot[i][j];
                r[k + 1] = p1[i][j];
                r[k + 2] = p2[i][j];
            }
    }
    __syncthreads();
    if (g == 0) {
        const float* r = &red[tl * 48];
        #pragma unroll
        for (int i = 0; i < TN; ++i) {
            int n = n0 + ln + 8 * i;
            float xr = xrn[ln + 8 * i];
            #pragma unroll
            for (int j = 0; j < TM; ++j) {
                int k = (i * TM + j) * 3;
                float d = dot[i][j] + r[k + 0];
                float a = p1 [i][j] + r[k + 1];
                float q = p2 [i][j] + r[k + 2];
                int m = m0 + lm + 16 * j;
                float* o = out + ((size_t)n * M + m) * 3;
                o[0] = d * xr * yrn[lm + 16 * j];
                o[1] = a;
                o[2] = sqrtf(q);
            }
        }
    }
}

extern "C" void kernel_launch(void* const* d_in, const int* in_sizes, int n_in,
                              void* d_out, int out_size, void* d_ws, size_t ws_size,
                              hipStream_t stream) {
    const float* x = (const float*)d_in[0];
    const float* y = (const float*)d_in[1];
    float* out = (float*)d_out;

    const int R = in_sizes[0] / DDIM;   // B*N = 2048
    const int M = in_sizes[1] / DDIM;   // 512

    dim3 grid(R / BN, M / BM);          // (64, 8) = 512 blocks, 2 per CU
    distance_kernel<<<grid, 256, 0, stream>>>(x, y, out, R, M);
}

// Round 4
// 68.685 us; speedup vs baseline: 1.2752x; 1.2752x over previous
//
#include <hip/hip_runtime.h>
#include <math.h>

// Distance: out[b,n,m,{cos,p1,p2}], x[B,N,128], y[M,128], R=B*N rows.
// fp16 LDS tiles + v_dot2_f32_f16 (fp32 accum). p2/cos derived from the same
// dot via ||x-y||^2 = nx+ny-2dot. 2 VALU ops per pair-dim; LDS insts halved
// vs fp32 tiles. Block 32n x 64m, thread tile 2x4, 512 blocks (2/CU).

#define DDIM 128
#define BN 32
#define BM 64
#define PADH 136   // halves per LDS row: 272 B = 17*16 (b128-aligned), 4-bank row skew

typedef __fp16 h2 __attribute__((ext_vector_type(2)));   // matches cvt_pkrtz/fdot2

static __device__ __forceinline__ h2 habs2(h2 v) {
    unsigned u = __builtin_bit_cast(unsigned, v) & 0x7FFF7FFFu;
    return __builtin_bit_cast(h2, u);
}
static __device__ __forceinline__ h2 h2u(unsigned u) {
    return __builtin_bit_cast(h2, u);
}

__global__ __launch_bounds__(256, 2) void distance_kernel(
    const float* __restrict__ x, const float* __restrict__ y,
    float* __restrict__ out, int R, int M)
{
    __shared__ __align__(16) __fp16 xs[BN * PADH];
    __shared__ __align__(16) __fp16 ys[BM * PADH];
    __shared__ float nxs[BN];
    __shared__ float nys[BM];

    const int t  = threadIdx.x;
    const int n0 = blockIdx.x * BN;
    const int m0 = blockIdx.y * BM;

    // ---- Stage tiles: fp32 global -> fp16 LDS (coalesced float4 loads) ----
    {
        const float4* xg = (const float4*)(x + (size_t)n0 * DDIM);
        #pragma unroll
        for (int k = 0; k < (BN * DDIM / 4) / 256; ++k) {   // 4 iters
            int idx = t + 256 * k;
            int row = idx >> 5;
            int c   = idx & 31;                              // float4 index
            float4 v = xg[(row << 5) + c];
            h2 h0 = __builtin_amdgcn_cvt_pkrtz(v.x, v.y);
            h2 h1 = __builtin_amdgcn_cvt_pkrtz(v.z, v.w);
            uint2 w;
            w.x = __builtin_bit_cast(unsigned, h0);
            w.y = __builtin_bit_cast(unsigned, h1);
            *(uint2*)&xs[row * PADH + (c << 2)] = w;         // ds_write_b64
        }
        const float4* yg = (const float4*)(y + (size_t)m0 * DDIM);
        #pragma unroll
        for (int k = 0; k < (BM * DDIM / 4) / 256; ++k) {   // 8 iters
            int idx = t + 256 * k;
            int row = idx >> 5;
            int c   = idx & 31;
            float4 v = yg[(row << 5) + c];
            h2 h0 = __builtin_amdgcn_cvt_pkrtz(v.x, v.y);
            h2 h1 = __builtin_amdgcn_cvt_pkrtz(v.z, v.w);
            uint2 w;
            w.x = __builtin_bit_cast(unsigned, h0);
            w.y = __builtin_bit_cast(unsigned, h1);
            *(uint2*)&ys[row * PADH + (c << 2)] = w;
        }
    }
    __syncthreads();

    // ---- Cooperative per-row squared norms (fp32 accum over fp16 tiles) ----
    if (t < BN) {
        float s = 0.f;
        #pragma unroll
        for (int c = 0; c < DDIM / 8; ++c) {
            uint4 v = *(const uint4*)&xs[t * PADH + (c << 3)];
            h2 a = h2u(v.x), b = h2u(v.y), cc2 = h2u(v.z), d = h2u(v.w);
            s = __builtin_amdgcn_fdot2(a, a, s, false);
            s = __builtin_amdgcn_fdot2(b, b, s, false);
            s = __builtin_amdgcn_fdot2(cc2, cc2, s, false);
            s = __builtin_amdgcn_fdot2(d, d, s, false);
        }
        nxs[t] = s;
    } else if (t >= 64 && t < 64 + BM) {
        int row = t - 64;
        float s = 0.f;
        #pragma unroll
        for (int c = 0; c < DDIM / 8; ++c) {
            uint4 v = *(const uint4*)&ys[row * PADH + (c << 3)];
            h2 a = h2u(v.x), b = h2u(v.y), cc2 = h2u(v.z), d = h2u(v.w);
            s = __builtin_amdgcn_fdot2(a, a, s, false);
            s = __builtin_amdgcn_fdot2(b, b, s, false);
            s = __builtin_amdgcn_fdot2(cc2, cc2, s, false);
            s = __builtin_amdgcn_fdot2(d, d, s, false);
        }
        nys[row] = s;
    }
    __syncthreads();

    // ---- Main loop: thread (ln,lm) -> n = n0+ln+16i, m = m0+lm+16j ----
    const int lm = t & 15;
    const int ln = t >> 4;
    const h2 ones = h2u(0x3C003C00u);   // {1.0h, 1.0h}

    float dot[2][4] = {};
    float p1 [2][4] = {};

    #pragma unroll
    for (int c = 0; c < DDIM / 8; ++c) {           // 16 chunks of 8 dims
        uint4 xv[2], yv[4];
        xv[0] = *(const uint4*)&xs[ ln       * PADH + (c << 3)];   // ds_read_b128
        xv[1] = *(const uint4*)&xs[(ln + 16) * PADH + (c << 3)];
        #pragma unroll
        for (int j = 0; j < 4; ++j)
            yv[j] = *(const uint4*)&ys[(lm + 16 * j) * PADH + (c << 3)];

        #pragma unroll
        for (int i = 0; i < 2; ++i) {
            #pragma unroll
            for (int j = 0; j < 4; ++j) {
                const unsigned* xw = (const unsigned*)&xv[i];
                const unsigned* yw = (const unsigned*)&yv[j];
                #pragma unroll
                for (int k = 0; k < 4; ++k) {
                    h2 xh = h2u(xw[k]);
                    h2 yh = h2u(yw[k]);
                    h2 d  = xh - yh;                       // v_pk_add_f16 (sub)
                    dot[i][j] = __builtin_amdgcn_fdot2(xh, yh, dot[i][j], false);
                    p1 [i][j] = __builtin_amdgcn_fdot2(habs2(d), ones, p1[i][j], false);
                }
            }
        }
    }

    // ---- Epilogue: cos = dot*rsqrt(nx*ny); p2 = sqrt(nx+ny-2dot) ----
    #pragma unroll
    for (int i = 0; i < 2; ++i) {
        int n = n0 + ln + 16 * i;
        float nx = nxs[ln + 16 * i];
        #pragma unroll
        for (int j = 0; j < 4; ++j) {
            int m = m0 + lm + 16 * j;
            float ny = nys[lm + 16 * j];
            float d  = dot[i][j];
            float* o = out + ((size_t)n * M + m) * 3;
            o[0] = d * rsqrtf(nx * ny);
            o[1] = p1[i][j];
            o[2] = sqrtf(fmaxf(nx + ny - 2.f * d, 0.f));
        }
    }
}

extern "C" void kernel_launch(void* const* d_in, const int* in_sizes, int n_in,
                              void* d_out, int out_size, void* d_ws, size_t ws_size,
                              hipStream_t stream) {
    const float* x = (const float*)d_in[0];
    const float* y = (const float*)d_in[1];
    float* out = (float*)d_out;

    const int R = in_sizes[0] / DDIM;   // B*N = 2048
    const int M = in_sizes[1] / DDIM;   // 512

    dim3 grid(R / BN, M / BM);          // (64, 8) = 512 blocks, 2/CU
    distance_kernel<<<grid, 256, 0, stream>>>(x, y, out, R, M);
}